// Round 4
// baseline (202.380 us; speedup 1.0000x reference)
//
#include <hip/hip_runtime.h>
#include <hip/hip_bf16.h>

// MultiHeadAttention: B=2, S=2048, D=1024, H=16, key=head=64
// cvt_x (q,k,v fp32->bf16) ; transpose_w (W->W^T bf16, Wq pre-scaled 0.125*log2e)
// proj_gemm (bf16 A via global_load_lds, BK=32 dbuf, XCD-swizzled grid)
// transpose_v (vw -> vt[b][h][d][s]) ; attn_fwd (flash, MFMA32, 64qx32k wave tiles)

#define SEQ 2048
#define DIM 1024
#define NPROJ 1024

typedef __bf16 bf16x8 __attribute__((ext_vector_type(8)));
typedef float floatx4 __attribute__((ext_vector_type(4)));
typedef float floatx16 __attribute__((ext_vector_type(16)));

__device__ inline unsigned short f2bf_bits(float x) {
  __hip_bfloat16 h = __float2bfloat16(x);
  return __builtin_bit_cast(unsigned short, h);
}

__device__ __forceinline__ void gload_lds16(const void* g, void* l) {
  __builtin_amdgcn_global_load_lds((const __attribute__((address_space(1))) void*)g,
                                   (__attribute__((address_space(3))) void*)l, 16, 0, 0);
}
__device__ __forceinline__ void gload_lds4(const void* g, void* l) {
  __builtin_amdgcn_global_load_lds((const __attribute__((address_space(1))) void*)g,
                                   (__attribute__((address_space(3))) void*)l, 4, 0, 0);
}

// ---------------------------------------------------------------------------
// Kernel 0: q,k,v fp32 -> bf16
// ---------------------------------------------------------------------------
__global__ __launch_bounds__(256) void cvt_x(
    const float* __restrict__ q, const float* __restrict__ k, const float* __restrict__ v,
    unsigned short* __restrict__ xb)
{
  const float* X = blockIdx.z == 0 ? q : (blockIdx.z == 1 ? k : v);
  unsigned short* O = xb + (size_t)blockIdx.z * 4096 * 1024;
  int i0 = blockIdx.x * 256 + threadIdx.x;
  #pragma unroll
  for (int it = 0; it < 4; ++it) {
    int i = i0 + it * 262144;
    float4 f = *reinterpret_cast<const float4*>(&X[(size_t)i * 4]);
    ushort4 o;
    o.x = f2bf_bits(f.x); o.y = f2bf_bits(f.y);
    o.z = f2bf_bits(f.z); o.w = f2bf_bits(f.w);
    *reinterpret_cast<ushort4*>(&O[(size_t)i * 4]) = o;
  }
}

// ---------------------------------------------------------------------------
// Kernel 1: W [1024x1024] fp32 -> W^T bf16; Wq scaled by 0.125*log2e
// ---------------------------------------------------------------------------
__global__ __launch_bounds__(256) void transpose_w(
    const float* __restrict__ Wq, const float* __restrict__ Wk, const float* __restrict__ Wv,
    unsigned short* __restrict__ WqT, unsigned short* __restrict__ WkT, unsigned short* __restrict__ WvT)
{
  const float* W = blockIdx.z == 0 ? Wq : (blockIdx.z == 1 ? Wk : Wv);
  unsigned short* WT = blockIdx.z == 0 ? WqT : (blockIdx.z == 1 ? WkT : WvT);
  const float sc = (blockIdx.z == 0) ? 0.1803368801f : 1.0f;
  __shared__ float tile[64][65];
  const int k0 = blockIdx.x * 64;
  const int n0 = blockIdx.y * 64;
  const int t = threadIdx.x;
  #pragma unroll
  for (int it = 0; it < 4; ++it) {
    int idx = t + (it << 8);
    int r = idx >> 4, c4 = (idx & 15) << 2;
    float4 v = *reinterpret_cast<const float4*>(&W[(k0 + r) * DIM + n0 + c4]);
    tile[r][c4 + 0] = v.x; tile[r][c4 + 1] = v.y;
    tile[r][c4 + 2] = v.z; tile[r][c4 + 3] = v.w;
  }
  __syncthreads();
  #pragma unroll
  for (int it = 0; it < 4; ++it) {
    int idx = t + (it << 8);
    int r = idx >> 4, c4 = (idx & 15) << 2;
    ushort4 o;
    o.x = f2bf_bits(tile[c4 + 0][r] * sc);
    o.y = f2bf_bits(tile[c4 + 1][r] * sc);
    o.z = f2bf_bits(tile[c4 + 2][r] * sc);
    o.w = f2bf_bits(tile[c4 + 3][r] * sc);
    *reinterpret_cast<ushort4*>(&WT[(n0 + r) * DIM + k0 + c4]) = o;
  }
}

// ---------------------------------------------------------------------------
// Kernel 2: Y = bf16( X @ W ), X bf16 [4096x1024], B = W^T bf16.
// ---------------------------------------------------------------------------
__global__ __launch_bounds__(256, 4) void proj_gemm(
    const unsigned short* __restrict__ xb,
    const unsigned short* __restrict__ WqT, const unsigned short* __restrict__ WkT,
    const unsigned short* __restrict__ WvT,
    unsigned short* __restrict__ qw, unsigned short* __restrict__ kw, unsigned short* __restrict__ vw)
{
  const unsigned short* X = xb + (size_t)blockIdx.z * 4096 * 1024;
  const unsigned short* WT = blockIdx.z == 0 ? WqT : (blockIdx.z == 1 ? WkT : WvT);
  unsigned short* Y = blockIdx.z == 0 ? qw : (blockIdx.z == 1 ? kw : vw);

  __shared__ unsigned short Al[2][128 * 32];
  __shared__ unsigned short Bl[2][128 * 32];

  const int m0 = blockIdx.x * 128, n0 = blockIdx.y * 128;
  const int t = threadIdx.x;
  const int lane = t & 63;
  const int wid = t >> 6;
  const int wm = (wid >> 1) << 6, wn = (wid & 1) << 6;
  const int qd = lane >> 4, ln = lane & 15;

  auto stage = [&](int ks, int bi) {
    const int kb = ks << 6;
    #pragma unroll
    for (int i = 0; i < 2; ++i) {
      int p = t + (i << 8);
      int r = p >> 2, c = p & 3;
      int f = (r + (r >> 2)) & 3;
      gload_lds16((const char*)X + (size_t)(m0 + r) * 2048 + kb + ((c ^ f) << 4),
                  (char*)&Al[bi][0] + p * 16);
      gload_lds16((const char*)WT + (size_t)(n0 + r) * 2048 + kb + ((c ^ f) << 4),
                  (char*)&Bl[bi][0] + p * 16);
    }
  };

  floatx4 acc[4][4] = {};
  stage(0, 0);

  for (int ks = 0; ks < 32; ++ks) {
    __syncthreads();
    if (ks + 1 < 32) stage(ks + 1, (ks + 1) & 1);
    const int bi = ks & 1;
    bf16x8 af[4], bfr[4];
    #pragma unroll
    for (int mb = 0; mb < 4; ++mb) {
      int m = wm + mb * 16 + ln;
      int fm = (m + (m >> 2)) & 3;
      af[mb] = *reinterpret_cast<const bf16x8*>(&Al[bi][m * 32 + ((qd ^ fm) << 3)]);
    }
    #pragma unroll
    for (int nb = 0; nb < 4; ++nb) {
      int n = wn + nb * 16 + ln;
      int fn = (n + (n >> 2)) & 3;
      bfr[nb] = *reinterpret_cast<const bf16x8*>(&Bl[bi][n * 32 + ((qd ^ fn) << 3)]);
    }
    #pragma unroll
    for (int mb = 0; mb < 4; ++mb)
      #pragma unroll
      for (int nb = 0; nb < 4; ++nb)
        acc[mb][nb] = __builtin_amdgcn_mfma_f32_16x16x32_bf16(af[mb], bfr[nb], acc[mb][nb], 0, 0, 0);
  }
  #pragma unroll
  for (int mb = 0; mb < 4; ++mb)
    #pragma unroll
    for (int nb = 0; nb < 4; ++nb)
      #pragma unroll
      for (int i = 0; i < 4; ++i) {
        int m = m0 + wm + mb * 16 + qd * 4 + i;
        int n = n0 + wn + nb * 16 + ln;
        Y[(size_t)m * NPROJ + n] = f2bf_bits(acc[mb][nb][i]);
      }
}

// ---------------------------------------------------------------------------
// Kernel 3: vw [B*S][H*64] -> vt [B][H][64(d)][S], LDS-tiled 64x64
// ---------------------------------------------------------------------------
__global__ __launch_bounds__(256) void transpose_v(
    const unsigned short* __restrict__ vw, unsigned short* __restrict__ vt)
{
  __shared__ unsigned short tile[64 * 64];
  const int t = threadIdx.x;
  const int s0 = blockIdx.x * 64;
  const int bh = blockIdx.y;
  const int b = bh >> 4, h = bh & 15;
  #pragma unroll
  for (int it = 0; it < 2; ++it) {
    int p = t + (it << 8);
    int s = p >> 3, c = p & 7;
    int cp = (c + (s >> 3) + (s & 7)) & 7;
    *reinterpret_cast<int4*>(&tile[s * 64 + cp * 8]) =
        *reinterpret_cast<const int4*>(&vw[(size_t)(b * SEQ + s0 + s) * NPROJ + h * 64 + c * 8]);
  }
  __syncthreads();
  #pragma unroll
  for (int it = 0; it < 2; ++it) {
    int d = (t >> 3) + (it << 5), sc = t & 7;
    struct { alignas(16) unsigned short u[8]; } o;
    #pragma unroll
    for (int j = 0; j < 8; ++j) {
      int s = sc * 8 + j;
      int cp = ((d >> 3) + (s >> 3) + (s & 7)) & 7;
      o.u[j] = tile[s * 64 + cp * 8 + (d & 7)];
    }
    *reinterpret_cast<int4*>(&vt[(size_t)(bh * 64 + d) * SEQ + s0 + sc * 8]) =
        *reinterpret_cast<const int4*>(o.u);
  }
}

// ---------------------------------------------------------------------------
// Kernel 4: flash attention. grid (bh=32, q-tiles=16), 256 thr (4 waves).
// Wave tile: 64q x 32keys (2 m-blocks, self-owned key slice). MFMA 32x32x16.
// P quadrant wave-private (no exp->PV barrier). O/l partials combined at end.
// ---------------------------------------------------------------------------
__global__ __launch_bounds__(256, 2) void attn_fwd(
    const unsigned short* __restrict__ qw, const unsigned short* __restrict__ kw,
    const unsigned short* __restrict__ vt, const int* __restrict__ vmask,
    float* __restrict__ out)
{
  extern __shared__ char smem[];
  unsigned short* P  = (unsigned short*)smem;             // 128x64 bf16 = 16 KB (Q then P)
  unsigned short* Kl = (unsigned short*)(smem + 16384);   // 2 x 64x64 = 16 KB
  unsigned short* Vl = (unsigned short*)(smem + 32768);   // 16 KB
  int*   mk  = (int*)(smem + 49152);                      // 2 x 64 ints
  float* laS = (float*)(smem + 49664);                    // 128 floats
  float* Osc = (float*)(smem + 16384);                    // epilogue scratch (aliases Kl/Vl)

  const int t = threadIdx.x, lane = t & 63, wid = t >> 6;
  const int l5 = lane & 31, hi = lane >> 5;
  const int bh = blockIdx.x;
  const int q0 = blockIdx.y * 128;
  const int b = bh >> 4, h = bh & 15;
  const int base = b * SEQ;
  const int qh = (wid >> 1) * 64;   // wave's q half within tile
  const int ks = (wid & 1) * 32;    // wave's key slice within k-tile

  auto stage = [&](int kt, int bi) {
    const int k0 = kt << 6;
    #pragma unroll
    for (int i = 0; i < 2; ++i) {
      int rb = wid * 16 + i * 8;
      int r = rb + (lane >> 3);
      int sw = ((lane & 7) ^ (r & 7)) << 4;
      gload_lds16((const char*)kw + ((size_t)((base + k0 + r) * NPROJ + h * 64) << 1) + sw,
                  (char*)&Kl[bi * 4096] + rb * 128);
      gload_lds16((const char*)vt + ((size_t)((bh * 64 + r) * SEQ + k0) << 1) + sw,
                  (char*)&Vl[bi * 4096] + rb * 128);
    }
    if (wid == 0)
      gload_lds4((const char*)vmask + ((size_t)(base + k0 + lane) << 2), (char*)&mk[bi * 64]);
  };

  // stage Q (128x64) into P region, swizzled chunks
  #pragma unroll
  for (int i = 0; i < 4; ++i) {
    int idx = t + (i << 8);
    int r = idx >> 3, c = idx & 7;
    int pc = c ^ (r & 7);
    *reinterpret_cast<int4*>(&P[r * 64 + pc * 8]) =
        *reinterpret_cast<const int4*>(&qw[(size_t)((base + q0 + r) * NPROJ + h * 64 + c * 8)]);
  }
  stage(0, 0);
  __syncthreads();

  // preload Q fragments (2 m-blocks x 4 d-steps)
  bf16x8 qf[2][4];
  #pragma unroll
  for (int mb = 0; mb < 2; ++mb)
    #pragma unroll
    for (int kk = 0; kk < 4; ++kk) {
      int row = qh + mb * 32 + l5;
      int ch = (kk * 2 + hi) ^ (row & 7);
      qf[mb][kk] = *reinterpret_cast<const bf16x8*>(&P[row * 64 + ch * 8]);
    }

  bf16x8 ones;
  #pragma unroll
  for (int j = 0; j < 8; ++j) ones[j] = (__bf16)1.0f;

  floatx16 oa[2][2] = {};
  floatx16 la[2] = {};

  for (int kt = 0; kt < SEQ / 64; ++kt) {
    __syncthreads();                 // tile kt staged (barrier drains vmcnt); Q-frags read
    if (kt + 1 < SEQ / 64) stage(kt + 1, (kt + 1) & 1);
    const int bi = kt & 1;

    // S = Q K^T over this wave's 32-key slice
    floatx16 s[2] = {};
    #pragma unroll
    for (int kk = 0; kk < 4; ++kk) {
      int row = ks + l5;
      int ch = (kk * 2 + hi) ^ (row & 7);
      bf16x8 bk = *reinterpret_cast<const bf16x8*>(&Kl[bi * 4096 + row * 64 + ch * 8]);
      s[0] = __builtin_amdgcn_mfma_f32_32x32x16_bf16(qf[0][kk], bk, s[0], 0, 0, 0);
      s[1] = __builtin_amdgcn_mfma_f32_32x32x16_bf16(qf[1][kk], bk, s[1], 0, 0, 0);
    }

    // mask bias + exp2 + cheap bf16 pack into wave-private P quadrant
    const float bias = (mk[bi * 64 + ks + l5] != 0) ? 0.0f : -30000.0f;
    #pragma unroll
    for (int mb = 0; mb < 2; ++mb)
      #pragma unroll
      for (int r = 0; r < 16; ++r) {
        float p = __builtin_amdgcn_exp2f(s[mb][r] + bias);
        int row = qh + mb * 32 + (r & 3) + ((r >> 2) << 3) + (hi << 2);
        int col = ks + l5;
        unsigned bits = __builtin_bit_cast(unsigned, p) + 0x8000u;
        P[row * 64 + (((col >> 3) ^ (row & 7)) << 3) + (col & 7)] = (unsigned short)(bits >> 16);
      }

    // O += P V, l += P 1 over this wave's key slice (P quadrant self-owned)
    #pragma unroll
    for (int kk2 = 0; kk2 < 2; ++kk2) {
      bf16x8 ap[2], bv[2];
      int kA = ks + kk2 * 16 + hi * 8;
      #pragma unroll
      for (int mb = 0; mb < 2; ++mb) {
        int row = qh + mb * 32 + l5;
        ap[mb] = *reinterpret_cast<const bf16x8*>(&P[row * 64 + (((kA >> 3) ^ (row & 7)) << 3)]);
      }
      #pragma unroll
      for (int nb = 0; nb < 2; ++nb) {
        int row = nb * 32 + l5;
        bv[nb] = *reinterpret_cast<const bf16x8*>(&Vl[bi * 4096 + row * 64 + (((kA >> 3) ^ (row & 7)) << 3)]);
      }
      #pragma unroll
      for (int mb = 0; mb < 2; ++mb) {
        oa[mb][0] = __builtin_amdgcn_mfma_f32_32x32x16_bf16(ap[mb], bv[0], oa[mb][0], 0, 0, 0);
        oa[mb][1] = __builtin_amdgcn_mfma_f32_32x32x16_bf16(ap[mb], bv[1], oa[mb][1], 0, 0, 0);
        la[mb]    = __builtin_amdgcn_mfma_f32_32x32x16_bf16(ap[mb], ones,  la[mb],    0, 0, 0);
      }
    }
  }

  // epilogue: combine the two key-slice partials per q-half, normalize, store
  __syncthreads();                   // all waves done with Kl/Vl -> reuse as Osc
  const int half = qh >> 6;
  if (ks == 32) {
    #pragma unroll
    for (int mb = 0; mb < 2; ++mb)
      #pragma unroll
      for (int r = 0; r < 16; ++r) {
        int crow = mb * 32 + (r & 3) + ((r >> 2) << 3) + (hi << 2);
        #pragma unroll
        for (int nb = 0; nb < 2; ++nb)
          Osc[half * 4096 + crow * 64 + nb * 32 + l5] = oa[mb][nb][r];
        if (l5 == r) laS[qh + crow] = la[mb][r];
      }
  }
  __syncthreads();
  if (ks == 0) {
    #pragma unroll
    for (int mb = 0; mb < 2; ++mb)
      #pragma unroll
      for (int r = 0; r < 16; ++r) {
        int crow = mb * 32 + (r & 3) + ((r >> 2) << 3) + (hi << 2);
        float inv = 1.0f / (la[mb][r] + laS[qh + crow]);
        size_t o = (size_t)(base + q0 + qh + crow) * NPROJ + h * 64;
        #pragma unroll
        for (int nb = 0; nb < 2; ++nb) {
          float v = oa[mb][nb][r] + Osc[half * 4096 + crow * 64 + nb * 32 + l5];
          out[o + nb * 32 + l5] = v * inv;
        }
      }
  }
}

// ---------------------------------------------------------------------------
extern "C" void kernel_launch(void* const* d_in, const int* in_sizes, int n_in,
                              void* d_out, int out_size, void* d_ws, size_t ws_size,
                              hipStream_t stream) {
  const float* q  = (const float*)d_in[0];
  const float* k  = (const float*)d_in[1];
  const float* v  = (const float*)d_in[2];
  const int* vm   = (const int*)d_in[3];
  const float* Wq = (const float*)d_in[4];
  const float* Wk = (const float*)d_in[5];
  const float* Wv = (const float*)d_in[6];
  float* out = (float*)d_out;

  unsigned short* ws = (unsigned short*)d_ws;
  unsigned short* WqT = ws + ((size_t)0 << 20);
  unsigned short* WkT = ws + ((size_t)1 << 20);
  unsigned short* WvT = ws + ((size_t)2 << 20);
  unsigned short* qw  = ws + ((size_t)3 << 20);
  unsigned short* kw  = ws + ((size_t)7 << 20);
  unsigned short* vw  = ws + ((size_t)11 << 20);
  unsigned short* xb  = ws + ((size_t)15 << 20);  // 24 MB (3 bf16 planes)
  unsigned short* vt  = ws + ((size_t)15 << 20);  // aliases xb (xb dead before transpose_v)

  cvt_x<<<dim3(1024, 1, 3), 256, 0, stream>>>(q, k, v, xb);
  transpose_w<<<dim3(16, 16, 3), 256, 0, stream>>>(Wq, Wk, Wv, WqT, WkT, WvT);
  proj_gemm<<<dim3(32, 8, 3), 256, 0, stream>>>(xb, WqT, WkT, WvT, qw, kw, vw);
  transpose_v<<<dim3(32, 32), 256, 0, stream>>>(vw, vt);
  attn_fwd<<<dim3(32, 16), 256, 50176, stream>>>(qw, kw, vt, vm, out);
}

// Round 5
// 201.490 us; speedup vs baseline: 1.0044x; 1.0044x over previous
//
#include <hip/hip_runtime.h>
#include <hip/hip_bf16.h>

// MultiHeadAttention: B=2, S=2048, D=1024, H=16, key=head=64
// cvt_x -> transpose_w -> proj_gemm -> transpose_v (V^T frag-layout, mask-zeroed,
// kappa-permuted keys) -> attn_fwd (S^T register-P flash, key-split=2) -> combine

#define SEQ 2048
#define DIM 1024
#define NPROJ 1024

typedef __bf16 bf16x8 __attribute__((ext_vector_type(8)));
typedef float floatx4 __attribute__((ext_vector_type(4)));
typedef float floatx16 __attribute__((ext_vector_type(16)));
typedef unsigned uintx4 __attribute__((ext_vector_type(4)));

__device__ inline unsigned short f2bf_bits(float x) {
  __hip_bfloat16 h = __float2bfloat16(x);
  return __builtin_bit_cast(unsigned short, h);
}

__device__ __forceinline__ void gload_lds16(const void* g, void* l) {
  __builtin_amdgcn_global_load_lds((const __attribute__((address_space(1))) void*)g,
                                   (__attribute__((address_space(3))) void*)l, 16, 0, 0);
}
__device__ __forceinline__ void gload_lds4(const void* g, void* l) {
  __builtin_amdgcn_global_load_lds((const __attribute__((address_space(1))) void*)g,
                                   (__attribute__((address_space(3))) void*)l, 4, 0, 0);
}

// ---------------------------------------------------------------------------
// Kernel 0: q,k,v fp32 -> bf16
// ---------------------------------------------------------------------------
__global__ __launch_bounds__(256) void cvt_x(
    const float* __restrict__ q, const float* __restrict__ k, const float* __restrict__ v,
    unsigned short* __restrict__ xb)
{
  const float* X = blockIdx.z == 0 ? q : (blockIdx.z == 1 ? k : v);
  unsigned short* O = xb + (size_t)blockIdx.z * 4096 * 1024;
  int i0 = blockIdx.x * 256 + threadIdx.x;
  #pragma unroll
  for (int it = 0; it < 4; ++it) {
    int i = i0 + it * 262144;
    float4 f = *reinterpret_cast<const float4*>(&X[(size_t)i * 4]);
    ushort4 o;
    o.x = f2bf_bits(f.x); o.y = f2bf_bits(f.y);
    o.z = f2bf_bits(f.z); o.w = f2bf_bits(f.w);
    *reinterpret_cast<ushort4*>(&O[(size_t)i * 4]) = o;
  }
}

// ---------------------------------------------------------------------------
// Kernel 1: W [1024x1024] fp32 -> W^T bf16; Wq scaled by 0.125*log2e
// ---------------------------------------------------------------------------
__global__ __launch_bounds__(256) void transpose_w(
    const float* __restrict__ Wq, const float* __restrict__ Wk, const float* __restrict__ Wv,
    unsigned short* __restrict__ WqT, unsigned short* __restrict__ WkT, unsigned short* __restrict__ WvT)
{
  const float* W = blockIdx.z == 0 ? Wq : (blockIdx.z == 1 ? Wk : Wv);
  unsigned short* WT = blockIdx.z == 0 ? WqT : (blockIdx.z == 1 ? WkT : WvT);
  const float sc = (blockIdx.z == 0) ? 0.1803368801f : 1.0f;
  __shared__ float tile[64][65];
  const int k0 = blockIdx.x * 64;
  const int n0 = blockIdx.y * 64;
  const int t = threadIdx.x;
  #pragma unroll
  for (int it = 0; it < 4; ++it) {
    int idx = t + (it << 8);
    int r = idx >> 4, c4 = (idx & 15) << 2;
    float4 v = *reinterpret_cast<const float4*>(&W[(k0 + r) * DIM + n0 + c4]);
    tile[r][c4 + 0] = v.x; tile[r][c4 + 1] = v.y;
    tile[r][c4 + 2] = v.z; tile[r][c4 + 3] = v.w;
  }
  __syncthreads();
  #pragma unroll
  for (int it = 0; it < 4; ++it) {
    int idx = t + (it << 8);
    int r = idx >> 4, c4 = (idx & 15) << 2;
    ushort4 o;
    o.x = f2bf_bits(tile[c4 + 0][r] * sc);
    o.y = f2bf_bits(tile[c4 + 1][r] * sc);
    o.z = f2bf_bits(tile[c4 + 2][r] * sc);
    o.w = f2bf_bits(tile[c4 + 3][r] * sc);
    *reinterpret_cast<ushort4*>(&WT[(n0 + r) * DIM + k0 + c4]) = o;
  }
}

// ---------------------------------------------------------------------------
// Kernel 2: Y = bf16( X @ W )  (unchanged from r3)
// ---------------------------------------------------------------------------
__global__ __launch_bounds__(256, 4) void proj_gemm(
    const unsigned short* __restrict__ xb,
    const unsigned short* __restrict__ WqT, const unsigned short* __restrict__ WkT,
    const unsigned short* __restrict__ WvT,
    unsigned short* __restrict__ qw, unsigned short* __restrict__ kw, unsigned short* __restrict__ vw)
{
  const unsigned short* X = xb + (size_t)blockIdx.z * 4096 * 1024;
  const unsigned short* WT = blockIdx.z == 0 ? WqT : (blockIdx.z == 1 ? WkT : WvT);
  unsigned short* Y = blockIdx.z == 0 ? qw : (blockIdx.z == 1 ? kw : vw);

  __shared__ unsigned short Al[2][128 * 32];
  __shared__ unsigned short Bl[2][128 * 32];

  const int m0 = blockIdx.x * 128, n0 = blockIdx.y * 128;
  const int t = threadIdx.x;
  const int lane = t & 63;
  const int wid = t >> 6;
  const int wm = (wid >> 1) << 6, wn = (wid & 1) << 6;
  const int qd = lane >> 4, ln = lane & 15;

  auto stage = [&](int ks, int bi) {
    const int kb = ks << 6;
    #pragma unroll
    for (int i = 0; i < 2; ++i) {
      int p = t + (i << 8);
      int r = p >> 2, c = p & 3;
      int f = (r + (r >> 2)) & 3;
      gload_lds16((const char*)X + (size_t)(m0 + r) * 2048 + kb + ((c ^ f) << 4),
                  (char*)&Al[bi][0] + p * 16);
      gload_lds16((const char*)WT + (size_t)(n0 + r) * 2048 + kb + ((c ^ f) << 4),
                  (char*)&Bl[bi][0] + p * 16);
    }
  };

  floatx4 acc[4][4] = {};
  stage(0, 0);

  for (int ks = 0; ks < 32; ++ks) {
    __syncthreads();
    if (ks + 1 < 32) stage(ks + 1, (ks + 1) & 1);
    const int bi = ks & 1;
    bf16x8 af[4], bfr[4];
    #pragma unroll
    for (int mb = 0; mb < 4; ++mb) {
      int m = wm + mb * 16 + ln;
      int fm = (m + (m >> 2)) & 3;
      af[mb] = *reinterpret_cast<const bf16x8*>(&Al[bi][m * 32 + ((qd ^ fm) << 3)]);
    }
    #pragma unroll
    for (int nb = 0; nb < 4; ++nb) {
      int n = wn + nb * 16 + ln;
      int fn = (n + (n >> 2)) & 3;
      bfr[nb] = *reinterpret_cast<const bf16x8*>(&Bl[bi][n * 32 + ((qd ^ fn) << 3)]);
    }
    #pragma unroll
    for (int mb = 0; mb < 4; ++mb)
      #pragma unroll
      for (int nb = 0; nb < 4; ++nb)
        acc[mb][nb] = __builtin_amdgcn_mfma_f32_16x16x32_bf16(af[mb], bfr[nb], acc[mb][nb], 0, 0, 0);
  }
  #pragma unroll
  for (int mb = 0; mb < 4; ++mb)
    #pragma unroll
    for (int nb = 0; nb < 4; ++nb)
      #pragma unroll
      for (int i = 0; i < 4; ++i) {
        int m = m0 + wm + mb * 16 + qd * 4 + i;
        int n = n0 + wn + nb * 16 + ln;
        Y[(size_t)m * NPROJ + n] = f2bf_bits(acc[mb][nb][i]);
      }
}

// ---------------------------------------------------------------------------
// Kernel 3: vw -> vT in PV A-frag layout, keys kappa-permuted, mask-zeroed.
// vT[bh][kt][sg=kstep*2+hi][d64][8 keys]. Also mkT[b][kt*64+slot] (kappa order).
// ---------------------------------------------------------------------------
__global__ __launch_bounds__(256) void transpose_v(
    const unsigned short* __restrict__ vw, const int* __restrict__ vmask,
    unsigned short* __restrict__ vT, unsigned short* __restrict__ mkT)
{
  __shared__ unsigned short tile[64 * 64];
  __shared__ unsigned short msk[64];
  const int kt = blockIdx.x, bh = blockIdx.y;
  const int b = bh >> 4, h = bh & 15, t = threadIdx.x;
  if (t < 64) msk[t] = vmask[b * SEQ + kt * 64 + t] ? 0xFFFFu : 0;
  #pragma unroll
  for (int i = 0; i < 2; ++i) {
    int p = t + (i << 8);
    int key = p >> 3, o = p & 7;
    int os = o ^ (key & 7);
    *reinterpret_cast<int4*>(&tile[key * 64 + os * 8]) =
        *reinterpret_cast<const int4*>(&vw[(size_t)(b * SEQ + kt * 64 + key) * NPROJ + h * 64 + o * 8]);
  }
  __syncthreads();
  #pragma unroll
  for (int i = 0; i < 2; ++i) {
    int p = t + (i << 8);
    int d = p & 63, sg = p >> 6;           // sg = kstep*2 + hi
    int kstep = sg >> 1, hi = sg & 1;
    struct { alignas(16) unsigned short u[8]; } o;
    #pragma unroll
    for (int j = 0; j < 8; ++j) {
      int key16 = (j & 3) + 8 * (j >> 2) + 4 * hi;   // kappa(hi, j)
      int key = kstep * 16 + key16;
      int os = (d >> 3) ^ (key & 7);
      o.u[j] = tile[key * 64 + os * 8 + (d & 7)] & msk[key];
    }
    *reinterpret_cast<int4*>(&vT[(((size_t)(bh * 32 + kt) * 8 + sg) * 64 + d) * 8]) =
        *reinterpret_cast<const int4*>(o.u);
  }
  if (h == 0 && t < 64) {
    int kstep = t >> 4, s16 = t & 15, hi = s16 >> 3, j = s16 & 7;
    int key16 = (j & 3) + 8 * (j >> 2) + 4 * hi;
    mkT[(size_t)b * SEQ + kt * 64 + t] =
        vmask[b * SEQ + kt * 64 + kstep * 16 + key16] ? 0x3F80u : 0;
  }
}

// ---------------------------------------------------------------------------
// Kernel 4: flash attention, S^T register-P. grid (bh=32, qt=16, split=2),
// 256 thr = 4 waves x 32 queries. MFMA 32x32x16. K staged direct from kw
// (frag layout in LDS), V from vT, Q frags direct from qw.
// split 0 partials -> d_out (scrambled in-tile), split 1 -> Opart1; l -> lpart.
// ---------------------------------------------------------------------------
__global__ __launch_bounds__(256, 4) void attn_fwd(
    const unsigned short* __restrict__ qw, const unsigned short* __restrict__ kw,
    const unsigned short* __restrict__ vT, const unsigned short* __restrict__ mkT,
    float* __restrict__ out, float* __restrict__ Opart1, float* __restrict__ lpart)
{
  __shared__ unsigned short Kl[2][4096];   // [sg=dgroup*2+dhi][key64][8]
  __shared__ unsigned short Vl[2][4096];   // [sg=kstep*2+dhi][d64][8]
  __shared__ unsigned short mkl[2][64];

  const int t = threadIdx.x, lane = t & 63, wid = t >> 6;
  const int l31 = lane & 31, hi = lane >> 5;
  const int bh = blockIdx.x, qt = blockIdx.y, sp = blockIdx.z;
  const int b = bh >> 4, h = bh & 15;
  const int base = b * SEQ;
  const int qblk = qt * 4 + wid;           // 32-query block owned by this wave
  const int kt0 = sp * 16;

  // Q B-frags straight from qw (already frag-shaped: 8 consecutive d)
  bf16x8 qf[4];
  #pragma unroll
  for (int ks = 0; ks < 4; ++ks)
    qf[ks] = *reinterpret_cast<const bf16x8*>(
        &qw[(size_t)(base + qblk * 32 + l31) * NPROJ + h * 64 + ks * 16 + hi * 8]);

  auto stage = [&](int kt, int bi) {
    #pragma unroll
    for (int i = 0; i < 2; ++i) {
      int p = t + (i << 8);
      int key = p & 63, og = p >> 6;
      gload_lds16((const char*)&kw[(size_t)(base + kt * 64 + key) * NPROJ + h * 64 + og * 8],
                  (char*)&Kl[bi][0] + p * 16);
      gload_lds16((const char*)&vT[(size_t)(bh * 32 + kt) * 4096 + p * 8],
                  (char*)&Vl[bi][0] + p * 16);
    }
    if (t < 32)
      gload_lds4((const char*)(mkT + (size_t)b * SEQ + kt * 64) + t * 4,
                 (char*)&mkl[bi][0] + t * 4);
  };

  floatx16 oa[2] = {};
  floatx16 la = {};
  stage(kt0, 0);

  for (int it = 0; it < 16; ++it) {
    __syncthreads();                     // drains vmcnt: tile it ready
    if (it + 1 < 16) stage(kt0 + it + 1, (it + 1) & 1);
    const int bi = it & 1;

    // S^T = K Q^T  (m = key, n = query)
    floatx16 s[2] = {};
    #pragma unroll
    for (int ks = 0; ks < 4; ++ks) {
      const unsigned short* kb = &Kl[bi][(ks * 2 + hi) * 512];
      bf16x8 k0 = *reinterpret_cast<const bf16x8*>(&kb[l31 * 8]);
      bf16x8 k1 = *reinterpret_cast<const bf16x8*>(&kb[(32 + l31) * 8]);
      s[0] = __builtin_amdgcn_mfma_f32_32x32x16_bf16(k0, qf[ks], s[0], 0, 0, 0);
      s[1] = __builtin_amdgcn_mfma_f32_32x32x16_bf16(k1, qf[ks], s[1], 0, 0, 0);
    }

    // exp2 + round-half-up pack: C-reg pairs ARE the PV B-frag u32s (kappa order)
    unsigned pk[16];
    #pragma unroll
    for (int mb = 0; mb < 2; ++mb)
      #pragma unroll
      for (int r8 = 0; r8 < 2; ++r8)
        #pragma unroll
        for (int i = 0; i < 4; ++i) {
          float a = __builtin_amdgcn_exp2f(s[mb][r8 * 8 + i * 2]);
          float c = __builtin_amdgcn_exp2f(s[mb][r8 * 8 + i * 2 + 1]);
          unsigned ua = __builtin_bit_cast(unsigned, a) + 0x8000u;
          unsigned uc = __builtin_bit_cast(unsigned, c) + 0x8000u;
          pk[mb * 8 + r8 * 4 + i] = __builtin_amdgcn_perm(uc, ua, 0x07060302u);
        }

    // O^T += V^T P^T ; l += m . P^T
    #pragma unroll
    for (int kk = 0; kk < 4; ++kk) {
      uintx4 pv = {pk[kk * 4], pk[kk * 4 + 1], pk[kk * 4 + 2], pk[kk * 4 + 3]};
      bf16x8 pb = __builtin_bit_cast(bf16x8, pv);
      const unsigned short* vb = &Vl[bi][(kk * 2 + hi) * 512];
      bf16x8 v0 = *reinterpret_cast<const bf16x8*>(&vb[l31 * 8]);
      bf16x8 v1 = *reinterpret_cast<const bf16x8*>(&vb[(32 + l31) * 8]);
      bf16x8 mf = *reinterpret_cast<const bf16x8*>(&mkl[bi][kk * 16 + hi * 8]);
      oa[0] = __builtin_amdgcn_mfma_f32_32x32x16_bf16(v0, pb, oa[0], 0, 0, 0);
      oa[1] = __builtin_amdgcn_mfma_f32_32x32x16_bf16(v1, pb, oa[1], 0, 0, 0);
      la    = __builtin_amdgcn_mfma_f32_32x32x16_bf16(mf, pb, la, 0, 0, 0);
    }
  }

  // store partials (unnormalized O^T in MFMA layout; l per query)
  if (sp == 0) {
    size_t tb = (size_t)(base + qblk * 32) * NPROJ + h * 64;   // scrambled into out
    #pragma unroll
    for (int mb = 0; mb < 2; ++mb)
      #pragma unroll
      for (int r = 0; r < 16; ++r)
        out[tb + (size_t)(mb * 16 + r) * NPROJ + lane] = oa[mb][r];
    if (lane < 32)
      lpart[((size_t)bh * 64 + qblk) * 32 + l31] = la[0];
  } else {
    float* dst = Opart1 + ((size_t)bh * 64 + qblk) * 2048;
    #pragma unroll
    for (int mb = 0; mb < 2; ++mb)
      #pragma unroll
      for (int r = 0; r < 16; ++r)
        dst[(mb * 16 + r) * 64 + lane] = oa[mb][r];
    if (lane < 32)
      lpart[((size_t)(32 + bh) * 64 + qblk) * 32 + l31] = la[0];
  }
}

// ---------------------------------------------------------------------------
// Kernel 5: combine split partials, normalize, unscramble. grid (qblk64, bh32).
// ---------------------------------------------------------------------------
__global__ __launch_bounds__(256) void combine(
    const float* __restrict__ Opart1, const float* __restrict__ lpart,
    float* __restrict__ out)
{
  __shared__ float Os[32][68];
  __shared__ float ls[32];
  const int qblk = blockIdx.x, bh = blockIdx.y;
  const int b = bh >> 4, h = bh & 15, t = threadIdx.x;
  size_t tb = (size_t)(b * SEQ + qblk * 32) * NPROJ + h * 64;
  const float* o1 = Opart1 + ((size_t)bh * 64 + qblk) * 2048;
  if (t < 32)
    ls[t] = lpart[((size_t)bh * 64 + qblk) * 32 + t] +
            lpart[((size_t)(32 + bh) * 64 + qblk) * 32 + t];
  float v[8];
  int dd[8], qq[8];
  #pragma unroll
  for (int i = 0; i < 8; ++i) {
    int f = t + (i << 8);
    int ln = f & 63, mr = f >> 6;
    int mb = mr >> 4, reg = mr & 15;
    v[i] = out[tb + (size_t)mr * NPROJ + ln] + o1[f];
    dd[i] = (reg & 3) + ((reg >> 2) & 3) * 8 + (ln >> 5) * 4 + mb * 32;
    qq[i] = ln & 31;
  }
  __syncthreads();   // all tile reads from `out` done before overwrite
  #pragma unroll
  for (int i = 0; i < 8; ++i) Os[qq[i]][dd[i]] = v[i];
  __syncthreads();
  #pragma unroll
  for (int i = 0; i < 2; ++i) {
    int p = t + (i << 8);
    int q = p >> 4, c = p & 15;
    float inv = 1.0f / ls[q];
    float4 o = *reinterpret_cast<const float4*>(&Os[q][c * 4]);
    o.x *= inv; o.y *= inv; o.z *= inv; o.w *= inv;
    *reinterpret_cast<float4*>(&out[tb + (size_t)q * NPROJ + c * 4]) = o;
  }
}

// ---------------------------------------------------------------------------
extern "C" void kernel_launch(void* const* d_in, const int* in_sizes, int n_in,
                              void* d_out, int out_size, void* d_ws, size_t ws_size,
                              hipStream_t stream) {
  const float* q  = (const float*)d_in[0];
  const float* k  = (const float*)d_in[1];
  const float* v  = (const float*)d_in[2];
  const int* vm   = (const int*)d_in[3];
  const float* Wq = (const float*)d_in[4];
  const float* Wk = (const float*)d_in[5];
  const float* Wv = (const float*)d_in[6];
  float* out = (float*)d_out;

  unsigned short* ws = (unsigned short*)d_ws;
  // P3 layout: xb 0..12M | WqT 12M | WkT 13M | WvT 14M | qw 15M | kw 19M | vw 23M..27M
  unsigned short* xb  = ws;
  unsigned short* WqT = ws + ((size_t)12 << 20);
  unsigned short* WkT = ws + ((size_t)13 << 20);
  unsigned short* WvT = ws + ((size_t)14 << 20);
  unsigned short* qw  = ws + ((size_t)15 << 20);
  unsigned short* kw  = ws + ((size_t)19 << 20);
  unsigned short* vw  = ws + ((size_t)23 << 20);
  // P4/P5 reuse dead regions: vT over xb[0..4M); mkT at 4M; Opart1 at 4.5M (16.75MB);
  // lpart at 13.5M (over dead W*T). All within the proven 54 MB footprint.
  unsigned short* vT  = ws;
  unsigned short* mkT = ws + ((size_t)4 << 20);
  float* Opart1 = (float*)(ws + ((size_t)9 << 20) / 2 * 1);   // 4.5M units
  float* lpart  = (float*)(ws + ((size_t)27 << 19));          // 13.5M units

  cvt_x<<<dim3(1024, 1, 3), 256, 0, stream>>>(q, k, v, xb);
  transpose_w<<<dim3(16, 16, 3), 256, 0, stream>>>(Wq, Wk, Wv, WqT, WkT, WvT);
  proj_gemm<<<dim3(32, 8, 3), 256, 0, stream>>>(xb, WqT, WkT, WvT, qw, kw, vw);
  transpose_v<<<dim3(32, 32), 256, 0, stream>>>(vw, vm, vT, mkT);
  attn_fwd<<<dim3(32, 16, 2), 256, 0, stream>>>(qw, kw, vT, mkT, out, Opart1, lpart);
  combine<<<dim3(64, 32), 256, 0, stream>>>(Opart1, lpart, out);
}